// Round 11
// baseline (12644.761 us; speedup 1.0000x reference)
//
#include <hip/hip_runtime.h>

// Pendulum 3-layer LSTM (H=128), B=256 rows, 1024 sequential steps.
// Head collapsed to y = weff.h3 + beff (exact fp32 precompute).
// 128 blocks x 512 threads, 2 rows/block. Thread = (idx in 128, kq in 4).
//
// ROUND 11 = ROUND 10 with the DOT4 macro bug fixed (macro param `w`
// collided with the `.w` member accessor under preprocessor substitution;
// now a real inline function).
//
// Zero-VGPR weight streaming: ALL weights (L1+L2+L3, 640KB/step) stream via
// global_load_lds into a 16x8KB LDS ring; each wave stages and consumes its
// own 1KB slice -> wave-private, NO ring barriers. Counted vmcnt(12)/slot;
// 4-deep ds_read_b128 register read-ahead. Input x prefetched to LDS so the
// only vmcnt pollution is the 1-lane output store (provably safe: the
// needed load always has >=12 younger FIFO entries).
// 3-barrier cross-step pipeline kept verbatim (passed rounds 5-9, 2.44e-4).

typedef _Float16 f16;
typedef _Float16 f16x2 __attribute__((ext_vector_type(2)));
typedef unsigned int u32;

#define T_IN 512
#define T_TOT 1024
#define NBLK 128

__device__ __forceinline__ f16x2 u2h(u32 u) { return __builtin_bit_cast(f16x2, u); }

__device__ __forceinline__ float fdot2f(f16x2 a, f16x2 b, float c) {
#if __has_builtin(__builtin_amdgcn_fdot2)
  return __builtin_amdgcn_fdot2(a, b, c, false);
#else
  return c + (float)a[0] * (float)b[0] + (float)a[1] * (float)b[1];
#endif
}

__device__ __forceinline__ float frcp(float x) {
#if __has_builtin(__builtin_amdgcn_rcpf)
  return __builtin_amdgcn_rcpf(x);
#else
  return 1.f / x;
#endif
}
__device__ __forceinline__ float fsigm(float x) { return frcp(1.f + __expf(-x)); }
__device__ __forceinline__ float ftanh(float x) { return 1.f - 2.f * frcp(1.f + __expf(2.f * x)); }

__device__ __forceinline__ void dot4(float (&acc)[4], uint4 wv, u32 hv) {
  f16x2 hh = u2h(hv);
  acc[0] = fdot2f(u2h(wv.x), hh, acc[0]);
  acc[1] = fdot2f(u2h(wv.y), hh, acc[1]);
  acc[2] = fdot2f(u2h(wv.z), hh, acc[2]);
  acc[3] = fdot2f(u2h(wv.w), hh, acc[3]);
}

__device__ __forceinline__ void gl_lds16(const void* g, void* l) {
  __builtin_amdgcn_global_load_lds((const __attribute__((address_space(1))) u32*)g,
                                   (__attribute__((address_space(3))) u32*)l, 16, 0, 0);
}

// ---- weight packing -------------------------------------------------------
// Unified 80-slot/step stream, consumption order. dst u32[(s*512 + t)*4 + g],
// thread col t: idx = t>>2, kq = t&3.
//  s<48: q=s/6, rmd=s%6:
//    rmd<4:  L2 pair p = kq*32+4q+rmd over [Wih2|Whh2]  (K=[h1_new|h2_old])
//    rmd>=4: L3-early pair p = kq*16+2q+(rmd-4) of Whh3 (K=h3_old)
//  s>=48: j=(s-48)>>2, r=(s-48)&3:
//    r<2:  L3-late pair p = kq*16+2j+r     of Wih3      (K=h2_new)
//    r>=2: L1 pair  p = kq*16+2j+(r-2)     of Whh1      (K=h1, step s+1)
// u4 slot g holds half2{ W[g*128+idx][2p], W[g*128+idx][2p+1] }.
__global__ void pack_stream(u32* dst, const float* Wih2, const float* Whh2,
                            const float* Wih3, const float* Whh3,
                            const float* Whh1) {
  int tid = blockIdx.x * 256 + threadIdx.x;
  if (tid >= 80 * 512 * 4) return;
  int g = tid & 3;
  int t = (tid >> 2) & 511;
  int s = tid >> 11;
  int idx = t >> 2, kq = t & 3;
  const float* src;
  int p;
  if (s < 48) {
    int q = s / 6, rmd = s % 6;
    if (rmd < 4) {
      p = kq * 32 + 4 * q + rmd;
      if (p < 64) { src = Wih2; } else { src = Whh2; p -= 64; }
    } else {
      p = kq * 16 + 2 * q + (rmd - 4);
      src = Whh3;
    }
  } else {
    int j = (s - 48) >> 2, r = (s - 48) & 3;
    if (r < 2) { p = kq * 16 + 2 * j + r; src = Wih3; }
    else       { p = kq * 16 + 2 * j + (r - 2); src = Whh1; }
  }
  int jj = g * 128 + idx;
  union { f16 h[2]; u32 u; } cv;
  cv.h[0] = (f16)src[jj * 128 + 2 * p];
  cv.h[1] = (f16)src[jj * 128 + 2 * p + 1];
  dst[tid] = cv.u;
}

// consT[gg*512 + g*128 + idx]: gg 0=b1,1=b2,2=b3,3=wih1. [2048+idx]=weff, [2176]=beff.
__global__ void prep_cons(float* cons, const float* a1, const float* b1,
                          const float* a2, const float* b2,
                          const float* a3, const float* b3, const float* wih1) {
  int tid = blockIdx.x * 256 + threadIdx.x;
  if (tid >= 2048) return;
  int gg = tid >> 9, g = (tid >> 7) & 3, idx = tid & 127;
  int j = g * 128 + idx;
  float v;
  if (gg == 0) v = a1[j] + b1[j];
  else if (gg == 1) v = a2[j] + b2[j];
  else if (gg == 2) v = a3[j] + b3[j];
  else v = wih1[j];
  cons[tid] = v;
}

__global__ void head_fold(float* cons, const float* lin_w, const float* out_w,
                          const float* Wv, const float* bv,
                          const float* out_b, const float* lin_b) {
  __shared__ float wlo[128];
  __shared__ float pr[128];
  int j = threadIdx.x;
  float s = 0.f;
  for (int k = 0; k < 128; ++k) s += lin_w[k] * out_w[k * 128 + j];
  wlo[j] = s;
  __syncthreads();
  float t = 0.f;
  for (int k = 0; k < 128; ++k) t += wlo[k] * Wv[k * 128 + j];
  cons[2048 + j] = t;
  pr[j] = s * bv[j] + lin_w[j] * out_b[j];
  __syncthreads();
  if (j == 0) {
    float b = lin_b[0];
    for (int k = 0; k < 128; ++k) b += pr[k];
    cons[2176] = b;
  }
}

// Consume slot sl (weights in wbuf[sl&3], read 4 slots ago):
//   2x dot4, refill buffer sl&15 with slot (sl+16)%80 via global_load_lds,
//   counted vmcnt(12) (guarantees load for slot sl+4 complete), then
//   ds_read-ahead slot sl+4 into wbuf[sl&3].
#define CONSUME(sl, A0, A1, hv0, hv1)                                       \
  do {                                                                      \
    dot4(A0, wbuf[(sl) & 3], hv0);                                          \
    dot4(A1, wbuf[(sl) & 3], hv1);                                          \
    gl_lds16(WSt + (((sl) + 16) % 80) * 512, (void*)&ringL[(sl) & 15][wb]); \
    asm volatile("s_waitcnt vmcnt(12)" ::: "memory");                       \
    wbuf[(sl) & 3] = ringL[((sl) + 4) & 15][t];                             \
  } while (0)

// ---- main persistent kernel ----------------------------------------------
__global__ __launch_bounds__(512) void pendulum_persist(
    const float* __restrict__ input, const uint4* __restrict__ WS,
    const float* __restrict__ consG, float* __restrict__ out) {
  __shared__ __align__(16) uint4 ringL[16][512];  // 128 KB wave-sliced ring
  __shared__ __align__(16) f16 h1b[2][2][128];    // [parity][row][idx]
  __shared__ __align__(16) f16 h2b[2][2][128];
  __shared__ __align__(16) f16 h3b[2][128];       // [row][idx]
  __shared__ float xin[2][T_IN];                  // 4 KB input slab
  __shared__ float consL[2180];
  __shared__ float redp[2][8];

  const int t = threadIdx.x;
  const int idx = t >> 2;
  const int kq = t & 3;
  const int wb = t & 448;  // wave base (uniform per wave)
  const int row0 = blockIdx.x * 2, row1 = row0 + 1;

  for (int e = t; e < 2177; e += 512) consL[e] = consG[e];
  for (int e = t; e < 1024; e += 512)
    xin[e >> 9][e & 511] = input[(row0 + (e >> 9)) * T_IN + (e & 511)];
  if (t < 128) {
    h1b[0][0][t] = (f16)0.f; h1b[0][1][t] = (f16)0.f;
    h1b[1][0][t] = (f16)0.f; h1b[1][1][t] = (f16)0.f;
    h2b[0][0][t] = (f16)0.f; h2b[0][1][t] = (f16)0.f;
    h2b[1][0][t] = (f16)0.f; h2b[1][1][t] = (f16)0.f;
    h3b[0][t] = (f16)0.f;    h3b[1][t] = (f16)0.f;
  }

  const uint4* WSt = WS + t;

  float c1a = 0.f, c1b = 0.f, c2a = 0.f, c2b = 0.f, c3a = 0.f, c3b = 0.f;
  float y0 = 0.f, y1 = 0.f;
  __syncthreads();
  const float beffv = consL[2176];

  // prologue: step-0 layer1 (h1_old = 0 -> no dots)
  {
    float x0 = xin[0][0], x1 = xin[1][0];
    if (kq == 0) {
      float b0 = consL[idx], b2v = consL[256 + idx], b3v = consL[384 + idx];
      float w0 = consL[1536 + idx], w2w = consL[1792 + idx],
            w3w = consL[1920 + idx];
      {
        float ig = fsigm(b0 + x0 * w0);
        float gg = ftanh(b2v + x0 * w2w), og = fsigm(b3v + x0 * w3w);
        c1a = ig * gg; h1b[0][0][idx] = (f16)(og * ftanh(c1a));
      }
      {
        float ig = fsigm(b0 + x1 * w0);
        float gg = ftanh(b2v + x1 * w2w), og = fsigm(b3v + x1 * w3w);
        c1b = ig * gg; h1b[0][1][idx] = (f16)(og * ftanh(c1b));
      }
    }
    __syncthreads();
  }

  // ring prologue: stage slots 0..15, read-ahead slots 0..3 into registers
#pragma unroll
  for (int c = 0; c < 16; ++c) gl_lds16(WSt + c * 512, (void*)&ringL[c][wb]);
  asm volatile("s_waitcnt vmcnt(12)" ::: "memory");
  uint4 wbuf[4];
#pragma unroll
  for (int c = 0; c < 4; ++c) wbuf[c] = ringL[c][t];

  for (int s = 0; s < T_TOT; ++s) {
    const int par = s & 1;
    const int xi = (s + 1 < T_IN) ? (s + 1) : 0;
    float xl0 = xin[0][xi];
    float xl1 = xin[1][xi];

    const uint4* hL2r0 = (kq < 2)
        ? (const uint4*)&h1b[par][0][0] + kq * 8
        : (const uint4*)&h2b[par ^ 1][0][0] + (kq - 2) * 8;
    const uint4* hL2r1 = (kq < 2)
        ? (const uint4*)&h1b[par][1][0] + kq * 8
        : (const uint4*)&h2b[par ^ 1][1][0] + (kq - 2) * 8;
    const uint4* h3r0 = (const uint4*)&h3b[0][0] + kq * 4;
    const uint4* h3r1 = (const uint4*)&h3b[1][0] + kq * 4;

    float a2r0[4] = {0, 0, 0, 0}, a2r1[4] = {0, 0, 0, 0};
    float a3r0[4] = {0, 0, 0, 0}, a3r1[4] = {0, 0, 0, 0};

    // ---- P_A: slots 0..47 = L2 (4/q) + L3-early (2/q) ----
    uint4 E0, E1;
#pragma unroll
    for (int q = 0; q < 8; ++q) {
      uint4 H0 = hL2r0[q], H1 = hL2r1[q];
      u32 e0[4] = {H0.x, H0.y, H0.z, H0.w};
      u32 e1[4] = {H1.x, H1.y, H1.z, H1.w};
      if ((q & 1) == 0) { E0 = h3r0[q >> 1]; E1 = h3r1[q >> 1]; }
      CONSUME(6 * q + 0, a2r0, a2r1, e0[0], e1[0]);
      CONSUME(6 * q + 1, a2r0, a2r1, e0[1], e1[1]);
      CONSUME(6 * q + 2, a2r0, a2r1, e0[2], e1[2]);
      CONSUME(6 * q + 3, a2r0, a2r1, e0[3], e1[3]);
      u32 ea0 = (q & 1) ? E0.z : E0.x, ea1 = (q & 1) ? E1.z : E1.x;
      u32 eb0 = (q & 1) ? E0.w : E0.y, eb1 = (q & 1) ? E1.w : E1.y;
      CONSUME(6 * q + 4, a3r0, a3r1, ea0, ea1);
      CONSUME(6 * q + 5, a3r0, a3r1, eb0, eb1);
    }

    // L2 finish
#pragma unroll
    for (int g = 0; g < 4; ++g) {
      a2r0[g] += __shfl_xor(a2r0[g], 1, 64); a2r0[g] += __shfl_xor(a2r0[g], 2, 64);
      a2r1[g] += __shfl_xor(a2r1[g], 1, 64); a2r1[g] += __shfl_xor(a2r1[g], 2, 64);
    }
    if (kq == 0) {
      float b0 = consL[512 + idx], b1v = consL[640 + idx],
            b2v = consL[768 + idx], b3v = consL[896 + idx];
      {
        float ig = fsigm(a2r0[0] + b0), fg = fsigm(a2r0[1] + b1v);
        float gg = ftanh(a2r0[2] + b2v), og = fsigm(a2r0[3] + b3v);
        c2a = fg * c2a + ig * gg;
        h2b[par][0][idx] = (f16)(og * ftanh(c2a));
      }
      {
        float ig = fsigm(a2r1[0] + b0), fg = fsigm(a2r1[1] + b1v);
        float gg = ftanh(a2r1[2] + b2v), og = fsigm(a2r1[3] + b3v);
        c2b = fg * c2b + ig * gg;
        h2b[par][1][idx] = (f16)(og * ftanh(c2b));
      }
    }
    asm volatile("s_waitcnt lgkmcnt(0)\n\ts_barrier" ::: "memory");  // barrier1

    // ---- P_B: slots 48..79 = L3-late (2/j) + L1 for step s+1 (2/j) ----
    const uint4* hLTr0 = (const uint4*)&h2b[par][0][0] + kq * 4;
    const uint4* hLTr1 = (const uint4*)&h2b[par][1][0] + kq * 4;
    const uint4* h1r0 = (const uint4*)&h1b[par][0][0] + kq * 4;
    const uint4* h1r1 = (const uint4*)&h1b[par][1][0] + kq * 4;

    float a1r0[4] = {0, 0, 0, 0}, a1r1[4] = {0, 0, 0, 0};
    uint4 L0, L1v, F0, F1;
#pragma unroll
    for (int j = 0; j < 8; ++j) {
      if ((j & 1) == 0) {
        L0 = hLTr0[j >> 1]; L1v = hLTr1[j >> 1];
        F0 = h1r0[j >> 1];  F1 = h1r1[j >> 1];
      }
      u32 la0 = (j & 1) ? L0.z : L0.x, la1 = (j & 1) ? L1v.z : L1v.x;
      u32 lb0 = (j & 1) ? L0.w : L0.y, lb1 = (j & 1) ? L1v.w : L1v.y;
      u32 fa0 = (j & 1) ? F0.z : F0.x, fa1 = (j & 1) ? F1.z : F1.x;
      u32 fb0 = (j & 1) ? F0.w : F0.y, fb1 = (j & 1) ? F1.w : F1.y;
      CONSUME(48 + 4 * j + 0, a3r0, a3r1, la0, la1);
      CONSUME(48 + 4 * j + 1, a3r0, a3r1, lb0, lb1);
      CONSUME(48 + 4 * j + 2, a1r0, a1r1, fa0, fa1);
      CONSUME(48 + 4 * j + 3, a1r0, a1r1, fb0, fb1);
    }

#pragma unroll
    for (int g = 0; g < 4; ++g) {
      a3r0[g] += __shfl_xor(a3r0[g], 1, 64); a3r0[g] += __shfl_xor(a3r0[g], 2, 64);
      a3r1[g] += __shfl_xor(a3r1[g], 1, 64); a3r1[g] += __shfl_xor(a3r1[g], 2, 64);
      a1r0[g] += __shfl_xor(a1r0[g], 1, 64); a1r0[g] += __shfl_xor(a1r0[g], 2, 64);
      a1r1[g] += __shfl_xor(a1r1[g], 1, 64); a1r1[g] += __shfl_xor(a1r1[g], 2, 64);
    }

    // L3 finish + head partial
    float p0 = 0.f, p1 = 0.f;
    if (kq == 0) {
      float b0 = consL[1024 + idx], b1v = consL[1152 + idx],
            b2v = consL[1280 + idx], b3v = consL[1408 + idx];
      float weffr = consL[2048 + idx];
      {
        float ig = fsigm(a3r0[0] + b0), fg = fsigm(a3r0[1] + b1v);
        float gg = ftanh(a3r0[2] + b2v), og = fsigm(a3r0[3] + b3v);
        c3a = fg * c3a + ig * gg;
        float h3 = og * ftanh(c3a);
        h3b[0][idx] = (f16)h3;
        p0 = weffr * h3;
      }
      {
        float ig = fsigm(a3r1[0] + b0), fg = fsigm(a3r1[1] + b1v);
        float gg = ftanh(a3r1[2] + b2v), og = fsigm(a3r1[3] + b3v);
        c3b = fg * c3b + ig * gg;
        float h3 = og * ftanh(c3b);
        h3b[1][idx] = (f16)h3;
        p1 = weffr * h3;
      }
    }
#pragma unroll
    for (int k = 1; k < 64; k <<= 1) {
      p0 += __shfl_xor(p0, k, 64);
      p1 += __shfl_xor(p1, k, 64);
    }
    if ((t & 63) == 0) { redp[0][t >> 6] = p0; redp[1][t >> 6] = p1; }
    asm volatile("s_waitcnt lgkmcnt(0)\n\ts_barrier" ::: "memory");  // barrier2

    y0 = beffv; y1 = beffv;
#pragma unroll
    for (int w8 = 0; w8 < 8; ++w8) { y0 += redp[0][w8]; y1 += redp[1][w8]; }
    if (t == 0) out[row0 * T_TOT + s] = y0;
    else if (t == 1) out[row1 * T_TOT + s] = y1;

    // L1 finish for step s+1
    float xv0 = (s + 1 < T_IN) ? xl0 : y0;
    float xv1 = (s + 1 < T_IN) ? xl1 : y1;
    if (kq == 0) {
      float b0 = consL[idx], b1v = consL[128 + idx], b2v = consL[256 + idx],
            b3v = consL[384 + idx];
      float w0 = consL[1536 + idx], w1w = consL[1664 + idx],
            w2w = consL[1792 + idx], w3w = consL[1920 + idx];
      {
        float ig = fsigm(a1r0[0] + b0 + xv0 * w0), fg = fsigm(a1r0[1] + b1v + xv0 * w1w);
        float gg = ftanh(a1r0[2] + b2v + xv0 * w2w), og = fsigm(a1r0[3] + b3v + xv0 * w3w);
        c1a = fg * c1a + ig * gg;
        h1b[par ^ 1][0][idx] = (f16)(og * ftanh(c1a));
      }
      {
        float ig = fsigm(a1r1[0] + b0 + xv1 * w0), fg = fsigm(a1r1[1] + b1v + xv1 * w1w);
        float gg = ftanh(a1r1[2] + b2v + xv1 * w2w), og = fsigm(a1r1[3] + b3v + xv1 * w3w);
        c1b = fg * c1b + ig * gg;
        h1b[par ^ 1][1][idx] = (f16)(og * ftanh(c1b));
      }
    }
    asm volatile("s_waitcnt lgkmcnt(0)\n\ts_barrier" ::: "memory");  // barrier3
  }
}

// ---- launch ---------------------------------------------------------------
extern "C" void kernel_launch(void* const* d_in, const int* in_sizes, int n_in,
                              void* d_out, int out_size, void* d_ws, size_t ws_size,
                              hipStream_t stream) {
  const float* input = (const float*)d_in[0];
  const float* Wih1 = (const float*)d_in[2];
  const float* Whh1 = (const float*)d_in[3];
  const float* bih1 = (const float*)d_in[4];
  const float* bhh1 = (const float*)d_in[5];
  const float* Wih2 = (const float*)d_in[6];
  const float* Whh2 = (const float*)d_in[7];
  const float* bih2 = (const float*)d_in[8];
  const float* bhh2 = (const float*)d_in[9];
  const float* Wih3 = (const float*)d_in[10];
  const float* Whh3 = (const float*)d_in[11];
  const float* bih3 = (const float*)d_in[12];
  const float* bhh3 = (const float*)d_in[13];
  const float* in_proj_w = (const float*)d_in[14];
  const float* in_proj_b = (const float*)d_in[15];
  const float* out_w = (const float*)d_in[16];
  const float* out_b = (const float*)d_in[17];
  const float* lin_w = (const float*)d_in[18];
  const float* lin_b = (const float*)d_in[19];

  char* ws = (char*)d_ws;
  u32* WS = (u32*)(ws + (0 << 10));          // 640 KB unified stream
  float* consG = (float*)(ws + (640 << 10)); // ~8.7 KB

  pack_stream<<<640, 256, 0, stream>>>(WS, Wih2, Whh2, Wih3, Whh3, Whh1);
  prep_cons<<<8, 256, 0, stream>>>(consG, bih1, bhh1, bih2, bhh2, bih3, bhh3, Wih1);
  head_fold<<<1, 128, 0, stream>>>(consG, lin_w, out_w,
                                   in_proj_w + 2 * 128 * 128, in_proj_b + 256,
                                   out_b, lin_b);

  pendulum_persist<<<NBLK, 512, 0, stream>>>(
      input, (const uint4*)WS, consG, (float*)d_out);
}